// Round 7
// baseline (770.707 us; speedup 1.0000x reference)
//
#include <hip/hip_runtime.h>
#include <stdint.h>

// PAM_Module: B=8, C=512, H=W=64 -> N=4096, O=64. Dtype auto-detected (bf16 vs fp32).
// out = gamma * (vw @ (xf @ att^T) + vb) + x   (softmax rows sum to 1 => vb passes through)
// MFMA pipeline:
//   K0 detect, K1 prep (wt/bcat/vbf/gf fp32 + vw->bf16 vwb),
//   K2 proj -> Qb,Kb bf16 [b][n][64] (also writes xbf when input is fp32),
//   K3 attn_mfma: single-pass shifted-exp softmax + PV + fused vw-GEMM epilogue.
//
// R7 (concurrency fix): R6 profile showed all pipes <=21% busy and per-iter period
// 13.4k cyc vs 2.8k MFMA floor -- pipes run sequentially because 512-thr blocks at
// the 128-reg cap give only 2 lockstep barrier groups/CU and zero reg headroom.
//   - attn re-tiled to 32-i blocks, 256 thr (4 waves), same 64 AGPR acc + ~64 VGPR:
//     __launch_bounds__(256,4) -> 16 waves/CU = 4 INDEPENDENT blocks/CU.
//   - wave roles: p_compute quadrant (s=w&1, h2=w>>1); PV c-slice 128/wave
//     (two af[4] half-batches keep transients under the cap).
//   - xconv kernel removed: fp32 path writes xbf inside proj_qk (og==0 blocks);
//     bf16 path aliases xbf to x.
// ws: flag@0 gf@16 bcat@32 vbf@544 wt@2592 Qb@264736 Kb@4459040 vwb@8653344
//     xbf@9177632  (total 42,732,064 B)

#define B_ 8
#define C_ 512
#define N_ 4096

typedef unsigned short u16;
typedef unsigned int u32;
typedef __attribute__((ext_vector_type(8))) short bf16x8;
typedef __attribute__((ext_vector_type(4))) float f32x4;

static __device__ __forceinline__ float b2f(u16 u) {
    return __uint_as_float(((u32)u) << 16);
}
static __device__ __forceinline__ u16 f2b(float f) {
    u32 u = __float_as_uint(f);
    u = u + 0x7fffu + ((u >> 16) & 1u);   // RNE
    return (u16)(u >> 16);
}
static __device__ __forceinline__ float ldf(const void* p, size_t i, int fl) {
    return fl ? b2f(((const u16*)p)[i]) : ((const float*)p)[i];
}

// ---------------- kernel 0: dtype detector ----------------------------------------
__global__ void detect_dtype(const u16* __restrict__ x, int* __restrict__ flag) {
    __shared__ int cnt[256];
    int t = threadIdx.x;
    int c = 0;
    for (int i = t; i < 4096; i += 256) {
        int e = (x[i] >> 7) & 0xFF;
        if (e >= 95 && e <= 140) c++;
    }
    cnt[t] = c;
    __syncthreads();
    for (int s = 128; s > 0; s >>= 1) {
        if (t < s) cnt[t] += cnt[t + s];
        __syncthreads();
    }
    if (t == 0) *flag = (cnt[0] >= 3686) ? 1 : 0;   // 1 = bf16, 0 = fp32
}

// ---------------- kernel 1: params -> fp32 ws, vw -> bf16 --------------------------
__global__ void prep_params(const void* __restrict__ qw, const void* __restrict__ qb,
                            const void* __restrict__ kw, const void* __restrict__ kb,
                            const void* __restrict__ vb, const void* __restrict__ gm,
                            const void* __restrict__ vw, const int* __restrict__ flagp,
                            float* __restrict__ wt, float* __restrict__ bcat,
                            float* __restrict__ vbf, float* __restrict__ gf,
                            u16* __restrict__ vwb) {
    int fl = *flagp;
    int gid = blockIdx.x * 256 + threadIdx.x;   // grid 256*256 = 65536
    if (gid < C_ * 128) {
        int c = gid >> 7, o = gid & 127;
        wt[c * 128 + o] = (o < 64) ? ldf(qw, (size_t)o * C_ + c, fl)
                                   : ldf(kw, (size_t)(o - 64) * C_ + c, fl);
    }
    if (gid < 128) bcat[gid] = (gid < 64) ? ldf(qb, gid, fl) : ldf(kb, gid - 64, fl);
    if (gid < C_) vbf[gid] = ldf(vb, gid, fl);
    if (gid == 0) gf[0] = ldf(gm, 0, fl);
    {   // vw -> bf16: 65536 threads x 4 elems = 262144 = C*C
        int v0 = gid * 4;
        ushort4 h;
        h.x = f2b(ldf(vw, v0 + 0, fl));
        h.y = f2b(ldf(vw, v0 + 1, fl));
        h.z = f2b(ldf(vw, v0 + 2, fl));
        h.w = f2b(ldf(vw, v0 + 3, fl));
        *(ushort4*)(vwb + v0) = h;
    }
}

// ---------------- kernel 2: Q/K projection -> bf16, grid (2, 64, 8) ---------------
// fp32 input: og==0 blocks also emit x as bf16 into xbf (fuses the old xconv).
__global__ __launch_bounds__(256) void proj_qk(
        const void* __restrict__ xin, const int* __restrict__ flagp,
        const float* __restrict__ wt, const float* __restrict__ bcat,
        u16* __restrict__ Qb, u16* __restrict__ Kb, u16* __restrict__ xbf) {
    __shared__ __align__(16) char smem[32768];
    float* xs  = (float*)smem;            // [64][64]
    float* wsh = (float*)(smem + 16384);  // [64][64]
    const u16*   xb = (const u16*)xin;
    const float* xf = (const float*)xin;
    int fl = *flagp;

    int t = threadIdx.x;
    int og = blockIdx.x;
    int n0 = blockIdx.y * 64;
    int b  = blockIdx.z;
    int oc0 = og * 64;
    int tn = t & 15, to = t >> 4;

    float acc[4][4];
#pragma unroll
    for (int i = 0; i < 4; ++i)
#pragma unroll
        for (int j = 0; j < 4; ++j) acc[i][j] = 0.f;

    for (int c0 = 0; c0 < C_; c0 += 64) {
        __syncthreads();
        if (fl) {
#pragma unroll
            for (int rep = 0; rep < 4; ++rep) {
                int idx4 = rep * 256 + t;
                int cc = idx4 >> 4;
                int nn4 = (idx4 & 15) << 2;
                ushort4 uv = *(const ushort4*)(xb + ((size_t)(b * C_ + c0 + cc)) * N_ + n0 + nn4);
                float4 f;
                f.x = b2f(uv.x); f.y = b2f(uv.y); f.z = b2f(uv.z); f.w = b2f(uv.w);
                *(float4*)(xs + cc * 64 + nn4) = f;
            }
        } else {
#pragma unroll
            for (int rep = 0; rep < 4; ++rep) {
                int idx4 = rep * 256 + t;
                int cc = idx4 >> 4;
                int nn4 = (idx4 & 15) << 2;
                float4 v = *(const float4*)(xf + ((size_t)(b * C_ + c0 + cc)) * N_ + n0 + nn4);
                *(float4*)(xs + cc * 64 + nn4) = v;
                if (og == 0) {   // fused x -> bf16 (each (b,c,n) written exactly once)
                    ushort4 h;
                    h.x = f2b(v.x); h.y = f2b(v.y); h.z = f2b(v.z); h.w = f2b(v.w);
                    *(ushort4*)(xbf + ((size_t)(b * C_ + c0 + cc)) * N_ + n0 + nn4) = h;
                }
            }
        }
#pragma unroll
        for (int rep = 0; rep < 4; ++rep) {
            int idx4 = rep * 256 + t;
            int cc = idx4 >> 4;
            int oo4 = (idx4 & 15) << 2;
            *(float4*)(wsh + cc * 64 + oo4) =
                *(const float4*)(wt + (size_t)(c0 + cc) * 128 + oc0 + oo4);
        }
        __syncthreads();
#pragma unroll 8
        for (int cc = 0; cc < 64; ++cc) {
            float4 xa = *(const float4*)(xs + cc * 64 + (tn << 2));
            float4 wa = *(const float4*)(wsh + cc * 64 + (to << 2));
            acc[0][0] += xa.x * wa.x; acc[0][1] += xa.x * wa.y;
            acc[0][2] += xa.x * wa.z; acc[0][3] += xa.x * wa.w;
            acc[1][0] += xa.y * wa.x; acc[1][1] += xa.y * wa.y;
            acc[1][2] += xa.y * wa.z; acc[1][3] += xa.y * wa.w;
            acc[2][0] += xa.z * wa.x; acc[2][1] += xa.z * wa.y;
            acc[2][2] += xa.z * wa.z; acc[2][3] += xa.z * wa.w;
            acc[3][0] += xa.w * wa.x; acc[3][1] += xa.w * wa.y;
            acc[3][2] += xa.w * wa.z; acc[3][3] += xa.w * wa.w;
        }
    }

    float b0 = bcat[oc0 + (to << 2) + 0];
    float b1 = bcat[oc0 + (to << 2) + 1];
    float b2 = bcat[oc0 + (to << 2) + 2];
    float b3 = bcat[oc0 + (to << 2) + 3];
    u16* dst = (og == 0) ? Qb : Kb;
#pragma unroll
    for (int i = 0; i < 4; ++i) {
        int n = n0 + (tn << 2) + i;
        ushort4 h;
        h.x = f2b(acc[i][0] + b0); h.y = f2b(acc[i][1] + b1);
        h.z = f2b(acc[i][2] + b2); h.w = f2b(acc[i][3] + b3);
        *(ushort4*)(dst + ((size_t)b * N_ + n) * 64 + (to << 2)) = h;
    }
}

// ---------------- kernel 3: MFMA single-pass attention + fused vw epilogue --------
// grid (128, 8) remapped XCD-bijectively, 256 threads (4 waves), 4 blocks/CU.
// Block: i-rows [i0, i0+32). Wave w: p_compute quadrant (s=w&1 -> 16 i, h2=w>>1 ->
// 32 j of the 64-j tile); PV/epilogue c-slice [128w, 128w+128).
// LDS layout (byte offsets):
#define KS2A_OFF 0        // K buf A [64][72]u16    9216 B
#define KS2B_OFF 9216     // K buf B [64][72]u16    9216 B
#define PSA_OFF  18432    // P buf A [32][72]u16    4608 B
#define PSB_OFF  23040    // P buf B [32][72]u16    4608 B
#define YS_OFF   0        // epilogue ys [32][520]u16  33280 B (overlays all above)
#define LP_OFF   33280    // lpart [32][2] float      256 B
#define SMEM3    33536

#define SHIFT_C 20.0f     // softmax constant shift (overflow guard; result-invariant)

__global__ __launch_bounds__(256, 4) void attn_mfma(
        const u16* __restrict__ Qb, const u16* __restrict__ Kb,
        const u16* __restrict__ xbfw, const void* __restrict__ xin,
        const int* __restrict__ flagp,
        const u16* __restrict__ vwb, const float* __restrict__ vbf,
        const float* __restrict__ gf, void* __restrict__ outv) {
    __shared__ __align__(16) char smem[SMEM3];
    u16* Ks2A = (u16*)(smem + KS2A_OFF);
    u16* Ks2B = (u16*)(smem + KS2B_OFF);
    u16* PsA  = (u16*)(smem + PSA_OFF);
    u16* PsB  = (u16*)(smem + PSB_OFF);
    u16* ys   = (u16*)(smem + YS_OFF);
    float* lpart = (float*)(smem + LP_OFF);

    const u16*   xb = (const u16*)xin;
    const float* xf = (const float*)xin;
    const int fl = *flagp;
    const u16* xb16 = fl ? (const u16*)xin : xbfw;   // bf16 view of x

    const int t = threadIdx.x;
    const int wv = t >> 6;            // 0..3
    const int lane = t & 63;
    const int L = lane & 15;
    const int q = lane >> 4;
    const int s  = wv & 1;            // i-subtile of p_compute
    const int h2 = wv >> 1;           // j-half of p_compute

    // XCD-bijective remap: batch b pinned to XCD b (1024 blocks, 1024%8==0).
    const int gid  = blockIdx.y * 128 + blockIdx.x;
    const int ngid = (gid & 7) * 128 + (gid >> 3);
    const int b  = ngid >> 7;
    const int i0 = (ngid & 127) * 32;

    // Q fragments for this wave's 16 S-rows (i = i0 + 16s + L)
    const u16* qp = Qb + ((size_t)b * N_ + i0 + 16 * s + L) * 64;
    bf16x8 qf0 = *(const bf16x8*)(qp + 8 * q);
    bf16x8 qf1 = *(const bf16x8*)(qp + 32 + 8 * q);

    // per-lane partial row sums of exp(S - SHIFT_C); lane row i = 16s+4q+r
    float lsum[4];
#pragma unroll
    for (int r = 0; r < 4; ++r) lsum[r] = 0.f;

    // acc[mt][nt]: y[c = 128wv+16mt+4q+r][i = 16nt+L]  (8 c-tiles x 2 i-tiles)
    f32x4 acc[8][2];
#pragma unroll
    for (int a = 0; a < 8; ++a)
#pragma unroll
        for (int nb = 0; nb < 2; ++nb) acc[a][nb] = (f32x4){0.f, 0.f, 0.f, 0.f};

    const int k2row = t >> 2, k2c = (t & 3) * 16;
    const u16* xrowA = xb16 + ((size_t)(b * C_ + 128 * wv + L)) * N_ + 8 * q;

    auto p_compute = [&](int jt) {
        const u16* kc2 = (jt & 1) ? Ks2B : Ks2A;
        u16* psw = (jt & 1) ? PsB : PsA;
        f32x4 sv[2];
#pragma unroll
        for (int h = 0; h < 2; ++h) {
            const u16* kr = kc2 + (16 * (2 * h2 + h) + L) * 72;
            bf16x8 k0 = *(const bf16x8*)(kr + 8 * q);
            bf16x8 k1 = *(const bf16x8*)(kr + 32 + 8 * q);
            f32x4 z = {0.f, 0.f, 0.f, 0.f};
            z = __builtin_amdgcn_mfma_f32_16x16x32_bf16(qf0, k0, z, 0, 0, 0);
            z = __builtin_amdgcn_mfma_f32_16x16x32_bf16(qf1, k1, z, 0, 0, 0);
            sv[h] = z;
        }
#pragma unroll
        for (int h = 0; h < 2; ++h)
#pragma unroll
            for (int r = 0; r < 4; ++r) {
                float p = __expf(sv[h][r] - SHIFT_C);   // unnormalized
                lsum[r] += p;
                psw[(16 * s + 4 * q + r) * 72 + 16 * (2 * h2 + h) + L] = f2b(p);
            }
    };

    auto pv_step = [&](int jtp) {
        const u16* psr = (jtp & 1) ? PsB : PsA;
        const int j0pv = jtp << 6;
#pragma unroll
        for (int ks = 0; ks < 2; ++ks) {
            bf16x8 pb0 = *(const bf16x8*)(psr + L * 72 + 32 * ks + 8 * q);
            bf16x8 pb1 = *(const bf16x8*)(psr + (16 + L) * 72 + 32 * ks + 8 * q);
            bf16x8 af[4];
#pragma unroll
            for (int mt = 0; mt < 4; ++mt)
                af[mt] = *(const bf16x8*)(xrowA + (size_t)(16 * mt) * N_
                                          + j0pv + 32 * ks);
            __builtin_amdgcn_s_setprio(1);
#pragma unroll
            for (int mt = 0; mt < 4; ++mt) {
                acc[mt][0] = __builtin_amdgcn_mfma_f32_16x16x32_bf16(
                    af[mt], pb0, acc[mt][0], 0, 0, 0);
                acc[mt][1] = __builtin_amdgcn_mfma_f32_16x16x32_bf16(
                    af[mt], pb1, acc[mt][1], 0, 0, 0);
            }
            __builtin_amdgcn_s_setprio(0);
#pragma unroll
            for (int mt = 0; mt < 4; ++mt)
                af[mt] = *(const bf16x8*)(xrowA + (size_t)(64 + 16 * mt) * N_
                                          + j0pv + 32 * ks);
            __builtin_amdgcn_s_setprio(1);
#pragma unroll
            for (int mt = 0; mt < 4; ++mt) {
                acc[4 + mt][0] = __builtin_amdgcn_mfma_f32_16x16x32_bf16(
                    af[mt], pb0, acc[4 + mt][0], 0, 0, 0);
                acc[4 + mt][1] = __builtin_amdgcn_mfma_f32_16x16x32_bf16(
                    af[mt], pb1, acc[4 + mt][1], 0, 0, 0);
            }
            __builtin_amdgcn_s_setprio(0);
        }
    };

    {   // stage K tile 0 -> Ks2A (256 thr x 2 uint4 = 8192 u16)
        const u16* kp = Kb + ((size_t)b * N_ + k2row) * 64 + k2c;
        *(uint4*)(Ks2A + k2row * 72 + k2c)     = *(const uint4*)kp;
        *(uint4*)(Ks2A + k2row * 72 + k2c + 8) = *(const uint4*)(kp + 8);
    }
    {   // peeled jt = 0: P(0) only
        const u16* kp = Kb + ((size_t)b * N_ + 64 + k2row) * 64 + k2c;
        uint4 kr0 = *(const uint4*)kp;
        uint4 kr1 = *(const uint4*)(kp + 8);
        __syncthreads();
        p_compute(0);
        *(uint4*)(Ks2B + k2row * 72 + k2c)     = kr0;
        *(uint4*)(Ks2B + k2row * 72 + k2c + 8) = kr1;
    }
    for (int jt = 1; jt < 64; ++jt) {
        uint4 kr0 = {0, 0, 0, 0}, kr1 = {0, 0, 0, 0};
        if (jt < 63) {   // prefetch K tile jt+1 (issued pre-barrier)
            const u16* kp = Kb + ((size_t)b * N_ + (jt + 1) * 64 + k2row) * 64 + k2c;
            kr0 = *(const uint4*)kp;
            kr1 = *(const uint4*)(kp + 8);
        }
        __syncthreads();
        p_compute(jt);
        if (jt < 63) {
            u16* kn = ((jt + 1) & 1) ? Ks2B : Ks2A;
            *(uint4*)(kn + k2row * 72 + k2c)     = kr0;
            *(uint4*)(kn + k2row * 72 + k2c + 8) = kr1;
        }
        pv_step(jt - 1);
    }
    __syncthreads();
    pv_step(63);   // flush the pipelined tile

    // ---- finalize l: reduce own-row partials over L lanes, combine j-halves -------
#pragma unroll
    for (int r = 0; r < 4; ++r) {
#pragma unroll
        for (int off = 8; off > 0; off >>= 1)
            lsum[r] += __shfl_xor(lsum[r], off, 64);
    }
    if (L == 0) {
#pragma unroll
        for (int r = 0; r < 4; ++r)
            lpart[(16 * s + 4 * q + r) * 2 + h2] = lsum[r];
    }
    __syncthreads();   // lpart visible; all Ps/Ks2 reads done (ys overlay safe)

    float fi[2];
#pragma unroll
    for (int nt = 0; nt < 2; ++nt) {
        int i = 16 * nt + L;
        fi[nt] = 1.0f / (lpart[i * 2] + lpart[i * 2 + 1]);
    }

    // ---- fused epilogue: z = vw @ y, out = gamma*(z+vb) + x ----
    // Write y (scaled by 1/l) once to ys[i][c], then barrier-free kc-GEMM.
#pragma unroll
    for (int mt = 0; mt < 8; ++mt)
#pragma unroll
        for (int nt = 0; nt < 2; ++nt) {
            ushort4 h;
            h.x = f2b(acc[mt][nt][0] * fi[nt]); h.y = f2b(acc[mt][nt][1] * fi[nt]);
            h.z = f2b(acc[mt][nt][2] * fi[nt]); h.w = f2b(acc[mt][nt][3] * fi[nt]);
            *(ushort4*)(ys + (16 * nt + L) * 520 + 128 * wv + 16 * mt + 4 * q) = h;
        }
    __syncthreads();

    const float gma = gf[0];
    f32x4 z[8][2];
#pragma unroll
    for (int a = 0; a < 8; ++a)
#pragma unroll
        for (int nb = 0; nb < 2; ++nb) z[a][nb] = (f32x4){0.f, 0.f, 0.f, 0.f};

#pragma unroll 1
    for (int kc = 0; kc < 8; ++kc) {
#pragma unroll
        for (int nn = 0; nn < 2; ++nn) {
            const u16* yr = ys + (16 * nn + L) * 520 + kc * 64;
            bf16x8 yb0 = *(const bf16x8*)(yr + 8 * q);
            bf16x8 yb1 = *(const bf16x8*)(yr + 32 + 8 * q);
#pragma unroll
            for (int mtp = 0; mtp < 8; ++mtp) {
                int crow = 128 * wv + 16 * mtp + L;
                const u16* wp = vwb + (size_t)crow * C_ + kc * 64;
                bf16x8 a0 = *(const bf16x8*)(wp + 8 * q);
                bf16x8 a1 = *(const bf16x8*)(wp + 32 + 8 * q);
                z[mtp][nn] = __builtin_amdgcn_mfma_f32_16x16x32_bf16(
                    a0, yb0, z[mtp][nn], 0, 0, 0);
                z[mtp][nn] = __builtin_amdgcn_mfma_f32_16x16x32_bf16(
                    a1, yb1, z[mtp][nn], 0, 0, 0);
            }
        }
    }
    // store
#pragma unroll
    for (int mtp = 0; mtp < 8; ++mtp)
#pragma unroll
        for (int nn = 0; nn < 2; ++nn)
#pragma unroll
            for (int r = 0; r < 4; ++r) {
                int cp = 128 * wv + 16 * mtp + 4 * q + r;
                int ii = i0 + 16 * nn + L;
                size_t oi = ((size_t)(b * C_ + cp)) * N_ + ii;
                float val = gma * (z[mtp][nn][r] + vbf[cp]);
                if (fl) ((u16*)outv)[oi] = f2b(val + b2f(xb[oi]));
                else    ((float*)outv)[oi] = val + xf[oi];
            }
}

extern "C" void kernel_launch(void* const* d_in, const int* in_sizes, int n_in,
                              void* d_out, int out_size, void* d_ws, size_t ws_size,
                              hipStream_t stream) {
    const void* x  = d_in[0];
    const void* qw = d_in[1];
    const void* qb = d_in[2];
    const void* kw = d_in[3];
    const void* kb = d_in[4];
    const void* vw = d_in[5];
    const void* vb = d_in[6];
    const void* gm = d_in[7];

    char* ws = (char*)d_ws;
    int*   flag = (int*)(ws + 0);
    float* gf   = (float*)(ws + 16);
    float* bcat = (float*)(ws + 32);
    float* vbf  = (float*)(ws + 544);
    float* wt   = (float*)(ws + 2592);
    u16*   Qb   = (u16*)(ws + 264736);
    u16*   Kb   = (u16*)(ws + 4459040);
    u16*   vwb  = (u16*)(ws + 8653344);
    u16*   xbf  = (u16*)(ws + 9177632);   // total ws use: 42,732,064 B

    detect_dtype<<<dim3(1), dim3(256), 0, stream>>>((const u16*)x, flag);
    prep_params<<<dim3(256), dim3(256), 0, stream>>>(
        qw, qb, kw, kb, vb, gm, vw, flag, wt, bcat, vbf, gf, vwb);
    proj_qk<<<dim3(2, 64, 8), dim3(256), 0, stream>>>(x, flag, wt, bcat, Qb, Kb, xbf);
    attn_mfma<<<dim3(128, 8), dim3(256), 0, stream>>>(
        Qb, Kb, xbf, x, flag, vwb, vbf, gf, d_out);
}

// Round 8
// 492.822 us; speedup vs baseline: 1.5639x; 1.5639x over previous
//
#include <hip/hip_runtime.h>
#include <stdint.h>

// PAM_Module: B=8, C=512, H=W=64 -> N=4096, O=64. Dtype auto-detected (bf16 vs fp32).
// out = gamma * (vw @ (xf @ att^T) + vb) + x   (softmax rows sum to 1 => vb passes through)
// MFMA pipeline:
//   K0 detect, K1 prep (wt/bcat/vbf/gf fp32 + vw->bf16 vwb),
//   K2 proj -> Qb,Kb bf16 [b][n][64] (fp32 path also writes xbf; bf16 aliases x),
//   K3 attn_mfma: single-pass shifted-exp softmax + PV + fused vw-GEMM epilogue.
//
// R8: revert R7's 256-thr re-tile (halved x-reuse, doubled VMEM -> 638us regression).
// Back to R6's verified shape (357us attn): 64-i blocks, 512 thr, acc[4][4],
// 4-MFMA-per-af-load reuse. New: j-tile 64 -> 128 => 32 iterations, HALF the
// barriers, 2x independent work between syncs (R6 showed pipes serializing around
// 64 barrier-synced iters: period 13.4k cyc vs 2.8k MFMA floor).
// LDS: K dbuf [128][72]x2 + Ps dbuf [64][136]x2 + lpart = 72.2 KB -> 2 blocks/CU.
// Keeps: __launch_bounds__(512,4) (64 VGPR + 64 AGPR = 128 -> 4 waves/SIMD),
// XCD-pinned batches, depth-2 P/PV pipeline, xconv fused into proj_qk.
// ws: flag@0 gf@16 bcat@32 vbf@544 wt@2592 Qb@264736 Kb@4459040 vwb@8653344
//     xbf@9177632  (total 42,732,064 B)

#define B_ 8
#define C_ 512
#define N_ 4096

typedef unsigned short u16;
typedef unsigned int u32;
typedef __attribute__((ext_vector_type(8))) short bf16x8;
typedef __attribute__((ext_vector_type(4))) float f32x4;

static __device__ __forceinline__ float b2f(u16 u) {
    return __uint_as_float(((u32)u) << 16);
}
static __device__ __forceinline__ u16 f2b(float f) {
    u32 u = __float_as_uint(f);
    u = u + 0x7fffu + ((u >> 16) & 1u);   // RNE
    return (u16)(u >> 16);
}
static __device__ __forceinline__ float ldf(const void* p, size_t i, int fl) {
    return fl ? b2f(((const u16*)p)[i]) : ((const float*)p)[i];
}

// ---------------- kernel 0: dtype detector ----------------------------------------
__global__ void detect_dtype(const u16* __restrict__ x, int* __restrict__ flag) {
    __shared__ int cnt[256];
    int t = threadIdx.x;
    int c = 0;
    for (int i = t; i < 4096; i += 256) {
        int e = (x[i] >> 7) & 0xFF;
        if (e >= 95 && e <= 140) c++;
    }
    cnt[t] = c;
    __syncthreads();
    for (int s = 128; s > 0; s >>= 1) {
        if (t < s) cnt[t] += cnt[t + s];
        __syncthreads();
    }
    if (t == 0) *flag = (cnt[0] >= 3686) ? 1 : 0;   // 1 = bf16, 0 = fp32
}

// ---------------- kernel 1: params -> fp32 ws, vw -> bf16 --------------------------
__global__ void prep_params(const void* __restrict__ qw, const void* __restrict__ qb,
                            const void* __restrict__ kw, const void* __restrict__ kb,
                            const void* __restrict__ vb, const void* __restrict__ gm,
                            const void* __restrict__ vw, const int* __restrict__ flagp,
                            float* __restrict__ wt, float* __restrict__ bcat,
                            float* __restrict__ vbf, float* __restrict__ gf,
                            u16* __restrict__ vwb) {
    int fl = *flagp;
    int gid = blockIdx.x * 256 + threadIdx.x;   // grid 256*256 = 65536
    if (gid < C_ * 128) {
        int c = gid >> 7, o = gid & 127;
        wt[c * 128 + o] = (o < 64) ? ldf(qw, (size_t)o * C_ + c, fl)
                                   : ldf(kw, (size_t)(o - 64) * C_ + c, fl);
    }
    if (gid < 128) bcat[gid] = (gid < 64) ? ldf(qb, gid, fl) : ldf(kb, gid - 64, fl);
    if (gid < C_) vbf[gid] = ldf(vb, gid, fl);
    if (gid == 0) gf[0] = ldf(gm, 0, fl);
    {   // vw -> bf16: 65536 threads x 4 elems = 262144 = C*C
        int v0 = gid * 4;
        ushort4 h;
        h.x = f2b(ldf(vw, v0 + 0, fl));
        h.y = f2b(ldf(vw, v0 + 1, fl));
        h.z = f2b(ldf(vw, v0 + 2, fl));
        h.w = f2b(ldf(vw, v0 + 3, fl));
        *(ushort4*)(vwb + v0) = h;
    }
}

// ---------------- kernel 2: Q/K projection -> bf16, grid (2, 64, 8) ---------------
// fp32 input: og==0 blocks also emit x as bf16 into xbf (fused xconv).
__global__ __launch_bounds__(256) void proj_qk(
        const void* __restrict__ xin, const int* __restrict__ flagp,
        const float* __restrict__ wt, const float* __restrict__ bcat,
        u16* __restrict__ Qb, u16* __restrict__ Kb, u16* __restrict__ xbf) {
    __shared__ __align__(16) char smem[32768];
    float* xs  = (float*)smem;            // [64][64]
    float* wsh = (float*)(smem + 16384);  // [64][64]
    const u16*   xb = (const u16*)xin;
    const float* xf = (const float*)xin;
    int fl = *flagp;

    int t = threadIdx.x;
    int og = blockIdx.x;
    int n0 = blockIdx.y * 64;
    int b  = blockIdx.z;
    int oc0 = og * 64;
    int tn = t & 15, to = t >> 4;

    float acc[4][4];
#pragma unroll
    for (int i = 0; i < 4; ++i)
#pragma unroll
        for (int j = 0; j < 4; ++j) acc[i][j] = 0.f;

    for (int c0 = 0; c0 < C_; c0 += 64) {
        __syncthreads();
        if (fl) {
#pragma unroll
            for (int rep = 0; rep < 4; ++rep) {
                int idx4 = rep * 256 + t;
                int cc = idx4 >> 4;
                int nn4 = (idx4 & 15) << 2;
                ushort4 uv = *(const ushort4*)(xb + ((size_t)(b * C_ + c0 + cc)) * N_ + n0 + nn4);
                float4 f;
                f.x = b2f(uv.x); f.y = b2f(uv.y); f.z = b2f(uv.z); f.w = b2f(uv.w);
                *(float4*)(xs + cc * 64 + nn4) = f;
            }
        } else {
#pragma unroll
            for (int rep = 0; rep < 4; ++rep) {
                int idx4 = rep * 256 + t;
                int cc = idx4 >> 4;
                int nn4 = (idx4 & 15) << 2;
                float4 v = *(const float4*)(xf + ((size_t)(b * C_ + c0 + cc)) * N_ + n0 + nn4);
                *(float4*)(xs + cc * 64 + nn4) = v;
                if (og == 0) {   // fused x -> bf16 (each (b,c,n) written exactly once)
                    ushort4 h;
                    h.x = f2b(v.x); h.y = f2b(v.y); h.z = f2b(v.z); h.w = f2b(v.w);
                    *(ushort4*)(xbf + ((size_t)(b * C_ + c0 + cc)) * N_ + n0 + nn4) = h;
                }
            }
        }
#pragma unroll
        for (int rep = 0; rep < 4; ++rep) {
            int idx4 = rep * 256 + t;
            int cc = idx4 >> 4;
            int oo4 = (idx4 & 15) << 2;
            *(float4*)(wsh + cc * 64 + oo4) =
                *(const float4*)(wt + (size_t)(c0 + cc) * 128 + oc0 + oo4);
        }
        __syncthreads();
#pragma unroll 8
        for (int cc = 0; cc < 64; ++cc) {
            float4 xa = *(const float4*)(xs + cc * 64 + (tn << 2));
            float4 wa = *(const float4*)(wsh + cc * 64 + (to << 2));
            acc[0][0] += xa.x * wa.x; acc[0][1] += xa.x * wa.y;
            acc[0][2] += xa.x * wa.z; acc[0][3] += xa.x * wa.w;
            acc[1][0] += xa.y * wa.x; acc[1][1] += xa.y * wa.y;
            acc[1][2] += xa.y * wa.z; acc[1][3] += xa.y * wa.w;
            acc[2][0] += xa.z * wa.x; acc[2][1] += xa.z * wa.y;
            acc[2][2] += xa.z * wa.z; acc[2][3] += xa.z * wa.w;
            acc[3][0] += xa.w * wa.x; acc[3][1] += xa.w * wa.y;
            acc[3][2] += xa.w * wa.z; acc[3][3] += xa.w * wa.w;
        }
    }

    float b0 = bcat[oc0 + (to << 2) + 0];
    float b1 = bcat[oc0 + (to << 2) + 1];
    float b2 = bcat[oc0 + (to << 2) + 2];
    float b3 = bcat[oc0 + (to << 2) + 3];
    u16* dst = (og == 0) ? Qb : Kb;
#pragma unroll
    for (int i = 0; i < 4; ++i) {
        int n = n0 + (tn << 2) + i;
        ushort4 h;
        h.x = f2b(acc[i][0] + b0); h.y = f2b(acc[i][1] + b1);
        h.z = f2b(acc[i][2] + b2); h.w = f2b(acc[i][3] + b3);
        *(ushort4*)(dst + ((size_t)b * N_ + n) * 64 + (to << 2)) = h;
    }
}

// ---------------- kernel 3: MFMA single-pass attention + fused vw epilogue --------
// grid (64, 8) remapped XCD-bijectively, 512 threads (8 waves), 2 blocks/CU.
// Block: i-rows [i0, i0+64). Wave w: p_compute tile (rt=w&3 -> 16 i-rows,
// h2=w>>2 -> 64-j half of the 128-j tile); PV/epilogue c-slice [64w, 64w+64).
// LDS layout (byte offsets):
#define KSA_OFF  0        // K buf A [128][72]u16  18432 B
#define KSB_OFF  18432    // K buf B [128][72]u16  18432 B
#define PSA_OFF  36864    // P buf A [64][136]u16  17408 B
#define PSB_OFF  54272    // P buf B [64][136]u16  17408 B
#define YS_OFF   0        // epilogue ys [64][520]u16  66560 B (overlays KS/Ps)
#define LP_OFF   71680    // lpart [64][2] float      512 B
#define SMEM3    72192

#define SHIFT_C 20.0f     // softmax constant shift (overflow guard; result-invariant)

__global__ __launch_bounds__(512, 4) void attn_mfma(
        const u16* __restrict__ Qb, const u16* __restrict__ Kb,
        const u16* __restrict__ xbfw, const void* __restrict__ xin,
        const int* __restrict__ flagp,
        const u16* __restrict__ vwb, const float* __restrict__ vbf,
        const float* __restrict__ gf, void* __restrict__ outv) {
    __shared__ __align__(16) char smem[SMEM3];
    u16* KsA = (u16*)(smem + KSA_OFF);
    u16* KsB = (u16*)(smem + KSB_OFF);
    u16* PsA = (u16*)(smem + PSA_OFF);
    u16* PsB = (u16*)(smem + PSB_OFF);
    u16* ys  = (u16*)(smem + YS_OFF);
    float* lpart = (float*)(smem + LP_OFF);

    const u16*   xb = (const u16*)xin;
    const float* xf = (const float*)xin;
    const int fl = *flagp;
    const u16* xb16 = fl ? (const u16*)xin : xbfw;   // bf16 view of x

    const int t = threadIdx.x;
    const int wv = t >> 6;
    const int lane = t & 63;
    const int L = lane & 15;
    const int q = lane >> 4;
    const int rt = wv & 3;            // i-subtile
    const int h2 = wv >> 2;           // j-half (64-wide) of the 128-j tile

    // XCD-bijective remap: batch b pinned to XCD b (512 blocks, 512%8==0).
    const int gid  = blockIdx.y * 64 + blockIdx.x;
    const int ngid = (gid & 7) * 64 + (gid >> 3);
    const int b  = ngid >> 6;
    const int i0 = (ngid & 63) * 64;

    // Q fragments for this wave's 16 S-rows (i = i0 + 16rt + L)
    const u16* qp = Qb + ((size_t)b * N_ + i0 + 16 * rt + L) * 64;
    bf16x8 qf0 = *(const bf16x8*)(qp + 8 * q);
    bf16x8 qf1 = *(const bf16x8*)(qp + 32 + 8 * q);

    // per-lane partial row sums of exp(S - SHIFT_C); lane row i = 16rt+4q+r
    float lsum[4];
#pragma unroll
    for (int r = 0; r < 4; ++r) lsum[r] = 0.f;

    // acc[mt][nt]: y[c = 64wv+16mt+4q+r][i = 16nt+L]
    f32x4 acc[4][4];
#pragma unroll
    for (int a = 0; a < 4; ++a)
#pragma unroll
        for (int nb = 0; nb < 4; ++nb) acc[a][nb] = (f32x4){0.f, 0.f, 0.f, 0.f};

    const int krow = t >> 2, kcol = (t & 3) * 16;   // K staging: 128 rows x 64 c
    const u16* xrow = xb16 + ((size_t)(b * C_ + 64 * wv + L)) * N_ + 8 * q;

    auto p_compute = [&](int jt) {
        const u16* kcur = (jt & 1) ? KsB : KsA;
        u16* psw = (jt & 1) ? PsB : PsA;
        f32x4 sv[4];
#pragma unroll
        for (int h = 0; h < 4; ++h) {
            const u16* kr = kcur + (64 * h2 + 16 * h + L) * 72;
            bf16x8 k0 = *(const bf16x8*)(kr + 8 * q);
            bf16x8 k1 = *(const bf16x8*)(kr + 32 + 8 * q);
            f32x4 z = {0.f, 0.f, 0.f, 0.f};
            z = __builtin_amdgcn_mfma_f32_16x16x32_bf16(qf0, k0, z, 0, 0, 0);
            z = __builtin_amdgcn_mfma_f32_16x16x32_bf16(qf1, k1, z, 0, 0, 0);
            sv[h] = z;
        }
#pragma unroll
        for (int h = 0; h < 4; ++h)
#pragma unroll
            for (int r = 0; r < 4; ++r) {
                float p = __expf(sv[h][r] - SHIFT_C);   // unnormalized
                lsum[r] += p;
                psw[(16 * rt + 4 * q + r) * 136 + 64 * h2 + 16 * h + L] = f2b(p);
            }
    };

    auto pv_step = [&](int jtp) {
        const u16* psr = (jtp & 1) ? PsB : PsA;
        const int j0pv = jtp << 7;
#pragma unroll
        for (int ks = 0; ks < 4; ++ks) {
            bf16x8 af[4];
#pragma unroll
            for (int mt = 0; mt < 4; ++mt)
                af[mt] = *(const bf16x8*)(xrow + (size_t)(16 * mt) * N_
                                          + j0pv + 32 * ks);
            __builtin_amdgcn_s_setprio(1);
#pragma unroll
            for (int nt = 0; nt < 4; ++nt) {
                bf16x8 pb = *(const bf16x8*)(psr + (16 * nt + L) * 136 + 32 * ks + 8 * q);
#pragma unroll
                for (int mt = 0; mt < 4; ++mt)
                    acc[mt][nt] = __builtin_amdgcn_mfma_f32_16x16x32_bf16(
                        af[mt], pb, acc[mt][nt], 0, 0, 0);
            }
            __builtin_amdgcn_s_setprio(0);
        }
    };

    {   // stage K tile 0 -> KsA (512 thr x 2 uint4: 128 rows x 64 c)
        const u16* kp = Kb + ((size_t)b * N_ + krow) * 64 + kcol;
        *(uint4*)(KsA + krow * 72 + kcol)     = *(const uint4*)kp;
        *(uint4*)(KsA + krow * 72 + kcol + 8) = *(const uint4*)(kp + 8);
    }
    {   // peeled jt = 0: P(0) only
        const u16* kp = Kb + ((size_t)b * N_ + 128 + krow) * 64 + kcol;
        uint4 kr0 = *(const uint4*)kp;
        uint4 kr1 = *(const uint4*)(kp + 8);
        __syncthreads();
        p_compute(0);
        *(uint4*)(KsB + krow * 72 + kcol)     = kr0;
        *(uint4*)(KsB + krow * 72 + kcol + 8) = kr1;
    }
    for (int jt = 1; jt < 32; ++jt) {
        uint4 kr0 = {0, 0, 0, 0}, kr1 = {0, 0, 0, 0};
        if (jt < 31) {   // prefetch K tile jt+1 (issued pre-barrier)
            const u16* kp = Kb + ((size_t)b * N_ + (jt + 1) * 128 + krow) * 64 + kcol;
            kr0 = *(const uint4*)kp;
            kr1 = *(const uint4*)(kp + 8);
        }
        __syncthreads();
        p_compute(jt);
        if (jt < 31) {
            u16* kn = ((jt + 1) & 1) ? KsB : KsA;
            *(uint4*)(kn + krow * 72 + kcol)     = kr0;
            *(uint4*)(kn + krow * 72 + kcol + 8) = kr1;
        }
        pv_step(jt - 1);
    }
    __syncthreads();
    pv_step(31);   // flush the pipelined tile

    // ---- finalize l: reduce own-row partials over L lanes, combine j-halves -------
#pragma unroll
    for (int r = 0; r < 4; ++r) {
#pragma unroll
        for (int off = 8; off > 0; off >>= 1)
            lsum[r] += __shfl_xor(lsum[r], off, 64);
    }
    if (L == 0) {
#pragma unroll
        for (int r = 0; r < 4; ++r)
            lpart[(16 * rt + 4 * q + r) * 2 + h2] = lsum[r];
    }
    __syncthreads();   // lpart visible; all Ps/Ks reads done (ys overlay safe)

    float fi[4];
#pragma unroll
    for (int nt = 0; nt < 4; ++nt) {
        int i = 16 * nt + L;
        fi[nt] = 1.0f / (lpart[i * 2] + lpart[i * 2 + 1]);
    }

    // ---- fused epilogue: z = vw @ y, out = gamma*(z+vb) + x ----
    // Write y (scaled by 1/l) once to ys[i][c], then barrier-free kc-GEMM.
#pragma unroll
    for (int mt = 0; mt < 4; ++mt)
#pragma unroll
        for (int nt = 0; nt < 4; ++nt) {
            ushort4 h;
            h.x = f2b(acc[mt][nt][0] * fi[nt]); h.y = f2b(acc[mt][nt][1] * fi[nt]);
            h.z = f2b(acc[mt][nt][2] * fi[nt]); h.w = f2b(acc[mt][nt][3] * fi[nt]);
            *(ushort4*)(ys + (16 * nt + L) * 520 + 64 * wv + 16 * mt + 4 * q) = h;
        }
    __syncthreads();

    const float gma = gf[0];
    f32x4 z[4][4];
#pragma unroll
    for (int a = 0; a < 4; ++a)
#pragma unroll
        for (int nb = 0; nb < 4; ++nb) z[a][nb] = (f32x4){0.f, 0.f, 0.f, 0.f};

#pragma unroll 1
    for (int kc = 0; kc < 8; ++kc) {
#pragma unroll
        for (int nn = 0; nn < 4; ++nn) {
            const u16* yr = ys + (16 * nn + L) * 520 + kc * 64;
            bf16x8 yb0 = *(const bf16x8*)(yr + 8 * q);
            bf16x8 yb1 = *(const bf16x8*)(yr + 32 + 8 * q);
#pragma unroll
            for (int mtp = 0; mtp < 4; ++mtp) {
                int crow = 64 * wv + 16 * mtp + L;
                const u16* wp = vwb + (size_t)crow * C_ + kc * 64;
                bf16x8 a0 = *(const bf16x8*)(wp + 8 * q);
                bf16x8 a1 = *(const bf16x8*)(wp + 32 + 8 * q);
                z[mtp][nn] = __builtin_amdgcn_mfma_f32_16x16x32_bf16(
                    a0, yb0, z[mtp][nn], 0, 0, 0);
                z[mtp][nn] = __builtin_amdgcn_mfma_f32_16x16x32_bf16(
                    a1, yb1, z[mtp][nn], 0, 0, 0);
            }
        }
    }
    // store
#pragma unroll
    for (int mtp = 0; mtp < 4; ++mtp)
#pragma unroll
        for (int nn = 0; nn < 4; ++nn)
#pragma unroll
            for (int r = 0; r < 4; ++r) {
                int cp = 64 * wv + 16 * mtp + 4 * q + r;
                int ii = i0 + 16 * nn + L;
                size_t oi = ((size_t)(b * C_ + cp)) * N_ + ii;
                float val = gma * (z[mtp][nn][r] + vbf[cp]);
                if (fl) ((u16*)outv)[oi] = f2b(val + b2f(xb[oi]));
                else    ((float*)outv)[oi] = val + xf[oi];
            }
}

extern "C" void kernel_launch(void* const* d_in, const int* in_sizes, int n_in,
                              void* d_out, int out_size, void* d_ws, size_t ws_size,
                              hipStream_t stream) {
    const void* x  = d_in[0];
    const void* qw = d_in[1];
    const void* qb = d_in[2];
    const void* kw = d_in[3];
    const void* kb = d_in[4];
    const void* vw = d_in[5];
    const void* vb = d_in[6];
    const void* gm = d_in[7];

    char* ws = (char*)d_ws;
    int*   flag = (int*)(ws + 0);
    float* gf   = (float*)(ws + 16);
    float* bcat = (float*)(ws + 32);
    float* vbf  = (float*)(ws + 544);
    float* wt   = (float*)(ws + 2592);
    u16*   Qb   = (u16*)(ws + 264736);
    u16*   Kb   = (u16*)(ws + 4459040);
    u16*   vwb  = (u16*)(ws + 8653344);
    u16*   xbf  = (u16*)(ws + 9177632);   // total ws use: 42,732,064 B

    detect_dtype<<<dim3(1), dim3(256), 0, stream>>>((const u16*)x, flag);
    prep_params<<<dim3(256), dim3(256), 0, stream>>>(
        qw, qb, kw, kb, vb, gm, vw, flag, wt, bcat, vbf, gf, vwb);
    proj_qk<<<dim3(2, 64, 8), dim3(256), 0, stream>>>(x, flag, wt, bcat, Qb, Kb, xbf);
    attn_mfma<<<dim3(64, 8), dim3(512), 0, stream>>>(
        Qb, Kb, xbf, x, flag, vwb, vbf, gf, d_out);
}